// Round 4
// baseline (678.800 us; speedup 1.0000x reference)
//
#include <hip/hip_runtime.h>
#include <stdint.h>

// GraphBlock_231928234690 — MI355X/gfx950, round 7
// f32 I/O; internal bf16 MFMA.
// NEW this round:
//  1. Packed h_last tile re-layout to CHUNK-MAJOR: t = c*2048 + k*16 + e*2
//     (c = j>>3, e = j&7). k_attn phase-C bfr loads become 256B-contiguous
//     (2 lines/instr, was 16); k_h writes the tile destination-ordered
//     (fully coalesced). Tile still rows 0..55 of (h,n) out slice (aliasing
//     argument unchanged).
//  2. k_attn phase B: depth-1 adj prefetch (hide scattered-load latency).
//  3. k_attn phase C: s_setprio(1) around MFMA cluster.
//  4. k_build + k_cast + 3x k_tr merged into ONE k_prep kernel (11->7 launches).
// ws layout unchanged (high water 116,581,376 B).

typedef unsigned short u16;
typedef __bf16 bf16;
typedef __bf16 bf16x8 __attribute__((ext_vector_type(8)));
typedef float f32x4 __attribute__((ext_vector_type(4)));

#define N_ 256
#define E_ 105
#define D_ 1024
#define H_ 8
#define DH_ 128
#define NE_ 26880

__device__ __forceinline__ u16 f2b(float f) { bf16 h = (bf16)f; return __builtin_bit_cast(u16, h); }
__device__ __forceinline__ float b2f(u16 u) { bf16 h = __builtin_bit_cast(bf16, u); return (float)h; }

#define AS1 __attribute__((address_space(1)))
#define AS3 __attribute__((address_space(3)))

__device__ __forceinline__ void load16_lds(const void* g, void* l) {
  __builtin_amdgcn_global_load_lds((AS1 void*)(unsigned long long)(uintptr_t)g,
                                   (AS3 void*)l, 16, 0, 0);
}

// ---------------------------------------------------------------------------
// 128x128 bf16 GEMM tile: C[128r x 128c] = A(128 x K) * B(128 x K)^T
// ---------------------------------------------------------------------------
__device__ __forceinline__ void gemm128(u16* lds, const u16* A, const u16* B, int K,
                                        int lda, int ldb, f32x4 (&acc)[4][4]) {
  u16* lA = lds;
  u16* lB = lds + 8192;
  const int tid  = threadIdx.x;
  const int lane = tid & 63;
  const int wave = tid >> 6;
  const int ln15 = lane & 15;
  const int lq   = lane >> 4;
  const int wRow = (wave >> 1) * 64;
  const int wCol = (wave & 1) * 64;

  const int iters = K >> 6;
  for (int kt = 0; kt < iters; ++kt) {
    const char* Ab = (const char*)A + kt * 128;
    const char* Bb = (const char*)B + kt * 128;
#pragma unroll
    for (int m = 0; m < 4; ++m) {
      int ci  = m * 256 + tid;
      int row = ci >> 3;
      int g   = (ci & 7) ^ (row & 7);
      char* dstA = (char*)lA + m * 4096 + wave * 1024;
      char* dstB = (char*)lB + m * 4096 + wave * 1024;
      load16_lds(Ab + (long)row * ((long)lda * 2) + g * 16, dstA);
      load16_lds(Bb + (long)row * ((long)ldb * 2) + g * 16, dstB);
    }
    __syncthreads();
#pragma unroll
    for (int ks = 0; ks < 2; ++ks) {
      const int cc = ks * 4 + lq;
      bf16x8 af[4], bfv[4];
#pragma unroll
      for (int i = 0; i < 4; ++i) {
        int r = wRow + i * 16 + ln15;
        af[i] = *(const bf16x8*)&lA[r * 64 + ((cc ^ (r & 7)) << 3)];
        int c = wCol + i * 16 + ln15;
        bfv[i] = *(const bf16x8*)&lB[c * 64 + ((cc ^ (c & 7)) << 3)];
      }
#pragma unroll
      for (int i = 0; i < 4; ++i)
#pragma unroll
        for (int j = 0; j < 4; ++j)
          acc[i][j] = __builtin_amdgcn_mfma_f32_16x16x32_bf16(af[i], bfv[j], acc[i][j], 0, 0, 0);
    }
    __syncthreads();
  }
}

__device__ __forceinline__ void zero_acc(f32x4 (&acc)[4][4]) {
  f32x4 z = {0.f, 0.f, 0.f, 0.f};
#pragma unroll
  for (int i = 0; i < 4; ++i)
#pragma unroll
    for (int j = 0; j < 4; ++j) acc[i][j] = z;
}

// ---------------------------------------------------------------------------
// k_prep: merged { k_build | k_cast(W->Wb) | tr(qW1) | tr(qW2) | tr(W[2]->Wt) }
// grid ranges: [0,13440) build, [13440,16512) cast, [16512,22656) trA,
//              [22656,24192) trB, [24192,25216) trC.  All independent.
// ---------------------------------------------------------------------------
__device__ __forceinline__ void tr_tile(const float* src, u16* dst, int R, int C,
                                        long sStr, long dStr, int bz, int bxy,
                                        u16 (*t)[33], int tid) {
  const int tilesC = C >> 5;
  const int tr = (bxy / tilesC) << 5;
  const int tc = (bxy % tilesC) << 5;
  const int lr = tid >> 5;
  const int lc = tid & 31;
#pragma unroll
  for (int i = 0; i < 4; ++i)
    t[lr + i * 8][lc] = f2b(src[bz * sStr + (long)(tr + lr + i * 8) * C + tc + lc]);
  __syncthreads();
#pragma unroll
  for (int i = 0; i < 4; ++i)
    dst[bz * dStr + (long)(tc + lr + i * 8) * R + tr + lc] = t[lc][lr + i * 8];
}

__global__ __launch_bounds__(256) void k_prep(const float* q, const float* para,
                                              const float* sent, const float* ent,
                                              const float* pm, const float* sm,
                                              const float* em, u16* x, float* nmask,
                                              const float* W, u16* Wb,
                                              const float* qW1, u16* qW1t,
                                              const float* qW2, u16* qW2t,
                                              u16* Wt) {
  __shared__ u16 t[32][33];
  const int b = blockIdx.x;
  const int tid = threadIdx.x;
  if (b < 13440) {
    long idx = (long)b * 256 + tid;
    int ne = (int)(idx >> 7), dc = (int)(idx & 127);
    int n = ne / E_, e = ne - n * E_;
    const float* src;
    if (e == 0)      src = q + (long)n * D_;
    else if (e < 5)  src = para + (long)(n * 4 + (e - 1)) * D_;
    else if (e < 45) src = sent + (long)(n * 40 + (e - 5)) * D_;
    else             src = ent + (long)(n * 60 + (e - 45)) * D_;
    float4 v0 = *(const float4*)(src + dc * 8);
    float4 v1 = *(const float4*)(src + dc * 8 + 4);
    uint4 o;
    o.x = (unsigned)f2b(v0.x) | ((unsigned)f2b(v0.y) << 16);
    o.y = (unsigned)f2b(v0.z) | ((unsigned)f2b(v0.w) << 16);
    o.z = (unsigned)f2b(v1.x) | ((unsigned)f2b(v1.y) << 16);
    o.w = (unsigned)f2b(v1.z) | ((unsigned)f2b(v1.w) << 16);
    *(uint4*)(x + (long)ne * D_ + dc * 8) = o;
    if (dc == 0) {
      float mv;
      if (e == 0)      mv = 1.f;
      else if (e < 5)  mv = pm[n * 4 + e - 1];
      else if (e < 45) mv = sm[n * 40 + e - 5];
      else             mv = em[n * 60 + e - 45];
      nmask[ne] = mv;
    }
  } else if (b < 16512) {
    long i = ((long)(b - 13440) * 256 + tid) * 4;
    float4 v = *(const float4*)(W + i);
    ushort4 o;
    o.x = f2b(v.x); o.y = f2b(v.y); o.z = f2b(v.z); o.w = f2b(v.w);
    *(ushort4*)(Wb + i) = o;
  } else if (b < 22656) {
    int idx = b - 16512;
    tr_tile(qW1, qW1t, 1024, 256, 262144, 262144, idx / 256, idx % 256, t, tid);
  } else if (b < 24192) {
    int idx = b - 22656;
    tr_tile(qW2, qW2t, 256, 256, 65536, 65536, idx / 64, idx % 64, t, tid);
  } else {
    int idx = b - 24192;
    tr_tile(W + 262144, Wt, 1024, 128, 393216, 131072, idx / 128, idx % 128, t, tid);
  }
}

// ---------------------------------------------------------------------------
__global__ __launch_bounds__(256) void k_qw1(const u16* x, const u16* qW1t, u16* r_bf) {
  __shared__ u16 shm[16384];
  const int bx = blockIdx.x;
  const int ht = bx >> 2, nt = (bx >> 1) & 1, mt = bx & 1;
  f32x4 acc[4][4];
  zero_acc(acc);
  gemm128(shm, x + (long)nt * 128 * (E_ * D_), qW1t + ((long)ht * 256 + mt * 128) * D_,
          1024, E_ * D_, 1024, acc);
  const int tid = threadIdx.x, lane = tid & 63, wave = tid >> 6;
  const int ln15 = lane & 15, lq = lane >> 4;
  const int wRow = (wave >> 1) * 64, wCol = (wave & 1) * 64;
#pragma unroll
  for (int rt = 0; rt < 4; ++rt)
#pragma unroll
    for (int ct = 0; ct < 4; ++ct)
#pragma unroll
      for (int rg = 0; rg < 4; ++rg) {
        int n = nt * 128 + wRow + rt * 16 + lq * 4 + rg;
        int m = mt * 128 + wCol + ct * 16 + ln15;
        float v = acc[rt][ct][rg];
        if (v < 0.f) v = 0.f;
        r_bf[((long)ht * 256 + n) * 256 + m] = f2b(v);
      }
}

// ---------------------------------------------------------------------------
__global__ __launch_bounds__(256) void k_qw2(const u16* r_bf, const u16* qW2t, const float* a,
                                             u16* ga) {
  __shared__ u16 shm[16384];
  const int bx = blockIdx.x;
  const int ht = bx >> 2, nt = (bx >> 1) & 1, mt = bx & 1;
  f32x4 acc[4][4];
  zero_acc(acc);
  gemm128(shm, r_bf + ((long)ht * 256 + nt * 128) * 256, qW2t + ((long)ht * 256 + mt * 128) * 256,
          256, 256, 256, acc);
  const int tid = threadIdx.x, lane = tid & 63, wave = tid >> 6;
  const int ln15 = lane & 15, lq = lane >> 4;
  const int wRow = (wave >> 1) * 64, wCol = (wave & 1) * 64;
#pragma unroll
  for (int rt = 0; rt < 4; ++rt)
#pragma unroll
    for (int ct = 0; ct < 4; ++ct)
#pragma unroll
      for (int rg = 0; rg < 4; ++rg) {
        int n = nt * 128 + wRow + rt * 16 + lq * 4 + rg;
        int m = mt * 128 + wCol + ct * 16 + ln15;
        float v = acc[rt][ct][rg];
        float sig = 1.f / (1.f + __expf(-v));
        float gv = sig * a[ht * 256 + m];
        int s = m >> 7, kk = m & 127;
        ga[(((long)ht * 2 + s) * 256 + n) * 128 + kk] = f2b(gv);
      }
}

// ---------------------------------------------------------------------------
__global__ __launch_bounds__(256) void k_w12(const u16* ga, const u16* Wb, u16* w12) {
  __shared__ u16 shm[16384];
  const int bx = blockIdx.x;
  const int c = bx >> 4, r2 = bx & 15;
  const int nt = r2 >> 3, dt = r2 & 7;
  const int ht = c >> 1;
  f32x4 acc[4][4];
  zero_acc(acc);
  gemm128(shm, ga + ((long)c * 256 + nt * 128) * 128, Wb + (long)ht * 131072 + dt * 128 * 128,
          128, 128, 128, acc);
  const int tid = threadIdx.x, lane = tid & 63, wave = tid >> 6;
  const int ln15 = lane & 15, lq = lane >> 4;
  const int wRow = (wave >> 1) * 64, wCol = (wave & 1) * 64;
#pragma unroll
  for (int rt = 0; rt < 4; ++rt)
#pragma unroll
    for (int ct = 0; ct < 4; ++ct)
#pragma unroll
      for (int rg = 0; rg < 4; ++rg) {
        int n = nt * 128 + wRow + rt * 16 + lq * 4 + rg;
        int d = dt * 128 + wCol + ct * 16 + ln15;
        w12[((long)n * 48 + c) * 1024 + d] = f2b(acc[rt][ct][rg]);
      }
}

// ---------------------------------------------------------------------------
__global__ __launch_bounds__(256) void k_f(const u16* x, const u16* w12, float* F) {
  __shared__ u16 shm[16384];
  const int n = blockIdx.x;
  f32x4 acc[4][4];
  zero_acc(acc);
  gemm128(shm, x + (long)n * E_ * D_, w12 + (long)n * 48 * 1024, 1024, 1024, 1024, acc);
  const int tid = threadIdx.x, lane = tid & 63, wave = tid >> 6;
  const int ln15 = lane & 15, lq = lane >> 4;
  const int wRow = (wave >> 1) * 64, wCol = (wave & 1) * 64;
#pragma unroll
  for (int rt = 0; rt < 4; ++rt)
#pragma unroll
    for (int ct = 0; ct < 4; ++ct)
#pragma unroll
      for (int rg = 0; rg < 4; ++rg) {
        int e = wRow + rt * 16 + lq * 4 + rg;
        int c = wCol + ct * 16 + ln15;
        if (e < 105 && c < 48) F[((long)n * 48 + c) * 105 + e] = acc[rt][ct][rg];
      }
}

// ---------------------------------------------------------------------------
// k_h: h_last -> packed transposed bf16 tile inside d_out, CHUNK-MAJOR layout:
//   u16 index t2 = c*1024 + k*8 + e   (c = j>>3 in [0,14), k in [0,128), e = j&7)
//   byte t = 2*t2; placed at out bytes ((n*105 + (t>>9))<<12) + (h<<9) + (t&511)
// (rows 0..55 of the (h,n) column slice — read then overwritten ONLY by k_attn
// block (h,n)). Final store loop iterates DESTINATION order => fully coalesced.
// ---------------------------------------------------------------------------
__global__ __launch_bounds__(256) void k_h(const u16* x, const u16* Wt, const float* nmask,
                                           float* out) {
  __shared__ u16 shm[16384];
  const int bx = blockIdx.x;
  const int h = bx / 210;
  const int ne0 = (bx % 210) * 128;
  f32x4 acc[4][4];
  zero_acc(acc);
  gemm128(shm, x + (long)ne0 * D_, Wt + (long)h * DH_ * D_, 1024, 1024, 1024, acc);
  const int tid = threadIdx.x, lane = tid & 63, wave = tid >> 6;
  const int ln15 = lane & 15, lq = lane >> 4;
  const int wRow = (wave >> 1) * 64, wCol = (wave & 1) * 64;
  // stage transposed bf16 tile: shm[k*128 + (nel ^ ((k&15)<<3))]
#pragma unroll
  for (int rt = 0; rt < 4; ++rt)
#pragma unroll
    for (int ct = 0; ct < 4; ++ct)
#pragma unroll
      for (int rg = 0; rg < 4; ++rg) {
        int nel = wRow + rt * 16 + lq * 4 + rg;
        int k   = wCol + ct * 16 + ln15;
        shm[k * 128 + (nel ^ ((k & 15) << 3))] = f2b(acc[rt][ct][rg]);
      }
  __syncthreads();
  char* ob = (char*)out;
  const int nStart = ne0 / 105;
  const int nEnd   = (ne0 + 127) / 105;
  for (int n = nStart; n <= nEnd; ++n) {
    const long tb = (((long)n * 105) << 12) + ((long)h << 9);
    const int pe = n * 105 + 104;                     // ne holding j=104
    const bool ownPad = (pe >= ne0) && (pe < ne0 + 128);
    for (int t2 = tid; t2 < 14336; t2 += 256) {
      int c = t2 >> 10;
      int r = t2 & 1023;
      int k = r >> 3, e = r & 7;
      int j = c * 8 + e;
      int t = t2 * 2;
      long gb = tb + (long)(t >> 9) * 4096 + (t & 511);
      if (j < 105) {
        int ne = n * 105 + j;
        if (ne >= ne0 && ne < ne0 + 128) {
          int nel = ne - ne0;
          u16 v = shm[k * 128 + (nel ^ ((k & 15) << 3))];
          float mv = nmask[ne];
          *(u16*)(ob + gb) = (mv != 0.f) ? v : (u16)0;
        }
      } else if (ownPad) {
        *(u16*)(ob + gb) = 0;                          // j = 105..111 pad
      }
    }
  }
}

// ---------------------------------------------------------------------------
// k_attn: per (h,n). Phase B: 16-lane-group softmax + depth-1 adj prefetch.
// Phase C: MFMA PV; B fragments = 256B-contiguous loads from chunk-major tile;
// s_setprio around MFMA. Phase D: LDS f32 restage -> coalesced float4 writes.
// LDS 31744 B. 2048 blocks.
// ---------------------------------------------------------------------------
__global__ __launch_bounds__(256) void k_attn(const float* F, const int* adj, const u16* x,
                                              float* out) {
  const int h = blockIdx.x >> 8;
  const int n = blockIdx.x & 255;
  __shared__ u16 cb[112 * 128];
  __shared__ float f1s[3][112];
  __shared__ float f2s[3][112];
  const int tid = threadIdx.x;
  const int lane = tid & 63, wave = tid >> 6;

  // ---- phase A: stage F rows, zero cb ----
  for (int i = tid; i < 630; i += 256) {
    int t = i / 210;
    int rm = i - t * 210;
    int s = rm / 105;
    int e = rm - s * 105;
    float v = F[((long)n * 48 + (h * 3 + t) * 2 + s) * 105 + e];
    if (s == 0) f1s[t][e] = v; else f2s[t][e] = v;
  }
  {
    unsigned* cbz = (unsigned*)cb;
    for (int i = tid; i < 112 * 64; i += 256) cbz[i] = 0;
  }
  __syncthreads();

  // ---- phase B: 16-lane groups; row i = it*16 + wave*4 + g; depth-1 prefetch ----
  {
    const int* abase = adj + (long)n * (E_ * E_);
    const int g  = lane >> 4;
    const int lg = lane & 15;
    float f2r[3][7];
#pragma unroll
    for (int m = 0; m < 7; ++m) {
      int j = lg + m * 16;
      bool jv = j < 105;
#pragma unroll
      for (int t = 0; t < 3; ++t) f2r[t][m] = jv ? f2s[t][j] : 0.f;
    }
    int avc[7];
    {
      int i0 = wave * 4 + g;                 // always < 32, valid
#pragma unroll
      for (int m = 0; m < 7; ++m) {
        int j = lg + m * 16;
        avc[m] = (j < 105) ? abase[i0 * E_ + j] : 0;
      }
    }
#pragma unroll
    for (int it = 0; it < 7; ++it) {
      int i = it * 16 + wave * 4 + g;
      bool iv = i < 105;
      int ir = iv ? i : 0;
      int avn[7];
      if (it < 6) {
        int in_ = i + 16;
        bool ivn = in_ < 105;
        int irn = ivn ? in_ : 0;
#pragma unroll
        for (int m = 0; m < 7; ++m) {
          int j = lg + m * 16;
          avn[m] = (ivn && j < 105) ? abase[irn * E_ + j] : 0;
        }
      }
      float f11 = f1s[0][ir], f12 = f1s[1][ir], f13 = f1s[2][ir];
      float s[7];
#pragma unroll
      for (int m = 0; m < 7; ++m) {
        int a_ = avc[m];
        float f1v = (a_ == 1) ? f11 : ((a_ == 2) ? f12 : f13);
        float f2v = (a_ == 1) ? f2r[0][m] : ((a_ == 2) ? f2r[1][m] : f2r[2][m]);
        float sv = f1v + f2v;
        sv = (sv < 0.f) ? 0.2f * sv : sv;
        s[m] = (a_ > 0) ? sv : -1e30f;
      }
      float mm = s[0];
#pragma unroll
      for (int m = 1; m < 7; ++m) mm = fmaxf(mm, s[m]);
#pragma unroll
      for (int d = 1; d < 16; d <<= 1) mm = fmaxf(mm, __shfl_xor(mm, d));
      float e[7];
      float sum = 0.f;
#pragma unroll
      for (int m = 0; m < 7; ++m) {
        int j = lg + m * 16;
        e[m] = (j < 105) ? __expf(s[m] - mm) : 0.f;
        sum += e[m];
      }
#pragma unroll
      for (int d = 1; d < 16; d <<= 1) sum += __shfl_xor(sum, d);
      float inv = 1.f / sum;
      if (iv) {
        const int rsw = i & 15;
#pragma unroll
        for (int m = 0; m < 7; ++m) {
          int j = lg + m * 16;
          if (j < 105)
            cb[i * 128 + ((((j >> 3) ^ rsw) << 3) + (j & 7))] = f2b(e[m] * inv);
        }
      }
      if (it < 6) {
#pragma unroll
        for (int m = 0; m < 7; ++m) avc[m] = avn[m];
      }
    }
  }
  __syncthreads();

  // ---- phase C: PV via MFMA; B fragments from chunk-major tile in d_out ----
  const char* hb = (const char*)out + (((long)n * 105) << 12) + ((long)h << 9);
  const int ln15 = lane & 15, lq = lane >> 4;
  const int nmt = (wave < 3) ? 2 : 1;
  f32x4 acc[2][8];
  {
    f32x4 z = {0.f, 0.f, 0.f, 0.f};
#pragma unroll
    for (int a_ = 0; a_ < 2; ++a_)
#pragma unroll
      for (int b_ = 0; b_ < 8; ++b_) acc[a_][b_] = z;
  }
#pragma unroll
  for (int ks = 0; ks < 4; ++ks) {
    const int cc = ks * 4 + lq;
    const int ccb = (cc < 14) ? cc : 0;  // clamp: matching A chunks are zero
    bf16x8 bfr[8];
#pragma unroll
    for (int jn = 0; jn < 8; ++jn) {
      int k = jn * 16 + ln15;
      bfr[jn] = *(const bf16x8*)(hb + (long)(ccb * 4 + (k >> 5)) * 4096 + (k & 31) * 16);
    }
    __builtin_amdgcn_s_setprio(1);
#pragma unroll
    for (int im = 0; im < 2; ++im) {
      if (im < nmt) {
        int i = (wave + im * 4) * 16 + ln15;
        bf16x8 af = *(const bf16x8*)&cb[i * 128 + ((cc ^ (i & 15)) << 3)];
#pragma unroll
        for (int jn = 0; jn < 8; ++jn)
          acc[im][jn] = __builtin_amdgcn_mfma_f32_16x16x32_bf16(af, bfr[jn], acc[im][jn], 0, 0, 0);
      }
    }
    __builtin_amdgcn_s_setprio(0);
  }
  // all MFMA reads (cb + packed tile) must complete before cb reuse / out writes
  __syncthreads();

  // ---- phase D: relu(acc) -> LDS f32 (stride 132) -> coalesced float4 writes ----
  float* sf = (float*)cb;
#pragma unroll
  for (int pass = 0; pass < 2; ++pass) {
    const int rbase = pass * 54;
    const int rcnt  = pass ? 51 : 54;
    for (int im = 0; im < nmt; ++im)
#pragma unroll
      for (int jn = 0; jn < 8; ++jn)
#pragma unroll
        for (int rg = 0; rg < 4; ++rg) {
          int i = (wave + im * 4) * 16 + lq * 4 + rg;
          if (i >= rbase && i < rbase + rcnt && i < 105) {
            int k = jn * 16 + ln15;
            float v = acc[im][jn][rg];
            sf[(i - rbase) * 132 + k] = v < 0.f ? 0.f : v;
          }
        }
    __syncthreads();
    for (int c = tid; c < rcnt * 32; c += 256) {
      int r = c >> 5, k4 = (c & 31) << 2;
      int i = rbase + r;
      float4 v = *(const float4*)&sf[r * 132 + k4];
      long xb = ((long)(n * E_ + i)) * D_ + h * DH_ + k4;
      ushort4 xv = *(const ushort4*)&x[xb];
      v.x += b2f(xv.x); v.y += b2f(xv.y); v.z += b2f(xv.z); v.w += b2f(xv.w);
      *(float4*)&out[xb] = v;
    }
    if (pass == 0) __syncthreads();
  }
}

// ---------------------------------------------------------------------------
extern "C" void kernel_launch(void* const* d_in, const int* in_sizes, int n_in,
                              void* d_out, int out_size, void* d_ws, size_t ws_size,
                              hipStream_t stream) {
  const float* q    = (const float*)d_in[0];
  const float* para = (const float*)d_in[1];
  const float* sent = (const float*)d_in[2];
  const float* ent  = (const float*)d_in[3];
  const float* pm   = (const float*)d_in[4];
  const float* sm   = (const float*)d_in[5];
  const float* em   = (const float*)d_in[6];
  const int*   adj  = (const int*)d_in[7];
  const float* W    = (const float*)d_in[8];
  const float* a    = (const float*)d_in[9];
  const float* qW1  = (const float*)d_in[10];
  const float* qW2  = (const float*)d_in[11];
  float* out = (float*)d_out;
  char* ws = (char*)d_ws;

  u16*   x     = (u16*)(ws);
  float* nmask = (float*)(ws + 55050240);
  u16*   Wb    = (u16*)(ws + 55682048);
  u16*   Wt    = (u16*)(ws + 61973504);
  u16*   qW1t  = (u16*)(ws + 64070656);
  u16*   qW2t  = (u16*)(ws + 76653568);
  u16*   r_bf  = (u16*)(ws + 79799296);
  u16*   ga    = (u16*)(ws + 82945024);
  u16*   w12   = (u16*)(ws + 86090752);
  float* F     = (float*)(ws + 111420416);

  k_prep<<<25216, 256, 0, stream>>>(q, para, sent, ent, pm, sm, em, x, nmask,
                                    W, Wb, qW1, qW1t, qW2, qW2t, Wt);
  k_qw1<<<96, 256, 0, stream>>>(x, qW1t, r_bf);
  k_qw2<<<96, 256, 0, stream>>>(r_bf, qW2t, a, ga);
  k_w12<<<768, 256, 0, stream>>>(ga, Wb, w12);
  k_f<<<256, 256, 0, stream>>>(x, w12, F);
  k_h<<<1680, 256, 0, stream>>>(x, Wt, nmask, out);
  k_attn<<<2048, 256, 0, stream>>>(F, adj, x, out);
}

// Round 5
// 654.537 us; speedup vs baseline: 1.0371x; 1.0371x over previous
//
#include <hip/hip_runtime.h>
#include <stdint.h>

// GraphBlock_231928234690 — MI355X/gfx950, round 8
// f32 I/O; internal bf16 MFMA.
// NEW this round:
//  1. REVERT k_prep merge -> separate k_build/k_cast/k_tr (r6 forms). The merged
//     kernel was the prime suspect for r7's +32us non-k_attn regression.
//  2. k_attn: operand-SWAPPED PV MFMA (mfma(bfr, af) -> C^T layout: lane holds
//     col i=ln15, rows k=lq*4+reg). Epilogue stores float4 DIRECTLY from acc
//     (+relu +residual): phase-D LDS restage and 3 barriers deleted.
//  3. k_attn: cb zeroing shrunk 28KB -> 3.4KB (ghost chunks 14/15 only); pad
//     cols j=105..111 written as exact zeros by unguarded phase-B store.
// k_h unchanged (chunk-major packed tile in d_out, proven in r7).
// ws layout unchanged (high water 116,581,376 B).

typedef unsigned short u16;
typedef __bf16 bf16;
typedef __bf16 bf16x8 __attribute__((ext_vector_type(8)));
typedef float f32x4 __attribute__((ext_vector_type(4)));

#define N_ 256
#define E_ 105
#define D_ 1024
#define H_ 8
#define DH_ 128
#define NE_ 26880

__device__ __forceinline__ u16 f2b(float f) { bf16 h = (bf16)f; return __builtin_bit_cast(u16, h); }
__device__ __forceinline__ float b2f(u16 u) { bf16 h = __builtin_bit_cast(bf16, u); return (float)h; }

#define AS1 __attribute__((address_space(1)))
#define AS3 __attribute__((address_space(3)))

__device__ __forceinline__ void load16_lds(const void* g, void* l) {
  __builtin_amdgcn_global_load_lds((AS1 void*)(unsigned long long)(uintptr_t)g,
                                   (AS3 void*)l, 16, 0, 0);
}

// ---------------------------------------------------------------------------
// 128x128 bf16 GEMM tile: C[128r x 128c] = A(128 x K) * B(128 x K)^T
// ---------------------------------------------------------------------------
__device__ __forceinline__ void gemm128(u16* lds, const u16* A, const u16* B, int K,
                                        int lda, int ldb, f32x4 (&acc)[4][4]) {
  u16* lA = lds;
  u16* lB = lds + 8192;
  const int tid  = threadIdx.x;
  const int lane = tid & 63;
  const int wave = tid >> 6;
  const int ln15 = lane & 15;
  const int lq   = lane >> 4;
  const int wRow = (wave >> 1) * 64;
  const int wCol = (wave & 1) * 64;

  const int iters = K >> 6;
  for (int kt = 0; kt < iters; ++kt) {
    const char* Ab = (const char*)A + kt * 128;
    const char* Bb = (const char*)B + kt * 128;
#pragma unroll
    for (int m = 0; m < 4; ++m) {
      int ci  = m * 256 + tid;
      int row = ci >> 3;
      int g   = (ci & 7) ^ (row & 7);
      char* dstA = (char*)lA + m * 4096 + wave * 1024;
      char* dstB = (char*)lB + m * 4096 + wave * 1024;
      load16_lds(Ab + (long)row * ((long)lda * 2) + g * 16, dstA);
      load16_lds(Bb + (long)row * ((long)ldb * 2) + g * 16, dstB);
    }
    __syncthreads();
#pragma unroll
    for (int ks = 0; ks < 2; ++ks) {
      const int cc = ks * 4 + lq;
      bf16x8 af[4], bfv[4];
#pragma unroll
      for (int i = 0; i < 4; ++i) {
        int r = wRow + i * 16 + ln15;
        af[i] = *(const bf16x8*)&lA[r * 64 + ((cc ^ (r & 7)) << 3)];
        int c = wCol + i * 16 + ln15;
        bfv[i] = *(const bf16x8*)&lB[c * 64 + ((cc ^ (c & 7)) << 3)];
      }
#pragma unroll
      for (int i = 0; i < 4; ++i)
#pragma unroll
        for (int j = 0; j < 4; ++j)
          acc[i][j] = __builtin_amdgcn_mfma_f32_16x16x32_bf16(af[i], bfv[j], acc[i][j], 0, 0, 0);
    }
    __syncthreads();
  }
}

__device__ __forceinline__ void zero_acc(f32x4 (&acc)[4][4]) {
  f32x4 z = {0.f, 0.f, 0.f, 0.f};
#pragma unroll
  for (int i = 0; i < 4; ++i)
#pragma unroll
    for (int j = 0; j < 4; ++j) acc[i][j] = z;
}

// ---------------------------------------------------------------------------
__global__ __launch_bounds__(256) void k_cast(const float* src, u16* dst, long n) {
  long i = ((long)blockIdx.x * 256 + threadIdx.x) * 4;
  if (i >= n) return;
  float4 v = *(const float4*)(src + i);
  ushort4 o;
  o.x = f2b(v.x); o.y = f2b(v.y); o.z = f2b(v.z); o.w = f2b(v.w);
  *(ushort4*)(dst + i) = o;
}

// ---------------------------------------------------------------------------
__global__ __launch_bounds__(256) void k_build(const float* q, const float* para,
                                               const float* sent, const float* ent,
                                               const float* pm, const float* sm,
                                               const float* em, u16* x, float* nmask) {
  long idx = (long)blockIdx.x * 256 + threadIdx.x;
  if (idx >= (long)NE_ * 128) return;
  int ne = (int)(idx >> 7), dc = (int)(idx & 127);
  int n = ne / E_, e = ne - n * E_;
  const float* src;
  if (e == 0)      src = q + (long)n * D_;
  else if (e < 5)  src = para + (long)(n * 4 + (e - 1)) * D_;
  else if (e < 45) src = sent + (long)(n * 40 + (e - 5)) * D_;
  else             src = ent + (long)(n * 60 + (e - 45)) * D_;
  float4 v0 = *(const float4*)(src + dc * 8);
  float4 v1 = *(const float4*)(src + dc * 8 + 4);
  uint4 o;
  o.x = (unsigned)f2b(v0.x) | ((unsigned)f2b(v0.y) << 16);
  o.y = (unsigned)f2b(v0.z) | ((unsigned)f2b(v0.w) << 16);
  o.z = (unsigned)f2b(v1.x) | ((unsigned)f2b(v1.y) << 16);
  o.w = (unsigned)f2b(v1.z) | ((unsigned)f2b(v1.w) << 16);
  *(uint4*)(x + (long)ne * D_ + dc * 8) = o;
  if (dc == 0) {
    float mv;
    if (e == 0)      mv = 1.f;
    else if (e < 5)  mv = pm[n * 4 + e - 1];
    else if (e < 45) mv = sm[n * 40 + e - 5];
    else             mv = em[n * 60 + e - 45];
    nmask[ne] = mv;
  }
}

// ---------------------------------------------------------------------------
__global__ __launch_bounds__(256) void k_tr(const float* src, u16* dst, int R, int C,
                                            long sStr, long dStr) {
  __shared__ u16 t[32][33];
  const int bz = blockIdx.y;
  const int tilesC = C >> 5;
  const int tr = (blockIdx.x / tilesC) << 5;
  const int tc = (blockIdx.x % tilesC) << 5;
  const int lr = threadIdx.x >> 5;
  const int lc = threadIdx.x & 31;
#pragma unroll
  for (int i = 0; i < 4; ++i)
    t[lr + i * 8][lc] = f2b(src[bz * sStr + (long)(tr + lr + i * 8) * C + tc + lc]);
  __syncthreads();
#pragma unroll
  for (int i = 0; i < 4; ++i)
    dst[bz * dStr + (long)(tc + lr + i * 8) * R + tr + lc] = t[lc][lr + i * 8];
}

// ---------------------------------------------------------------------------
__global__ __launch_bounds__(256) void k_qw1(const u16* x, const u16* qW1t, u16* r_bf) {
  __shared__ u16 shm[16384];
  const int bx = blockIdx.x;
  const int ht = bx >> 2, nt = (bx >> 1) & 1, mt = bx & 1;
  f32x4 acc[4][4];
  zero_acc(acc);
  gemm128(shm, x + (long)nt * 128 * (E_ * D_), qW1t + ((long)ht * 256 + mt * 128) * D_,
          1024, E_ * D_, 1024, acc);
  const int tid = threadIdx.x, lane = tid & 63, wave = tid >> 6;
  const int ln15 = lane & 15, lq = lane >> 4;
  const int wRow = (wave >> 1) * 64, wCol = (wave & 1) * 64;
#pragma unroll
  for (int rt = 0; rt < 4; ++rt)
#pragma unroll
    for (int ct = 0; ct < 4; ++ct)
#pragma unroll
      for (int rg = 0; rg < 4; ++rg) {
        int n = nt * 128 + wRow + rt * 16 + lq * 4 + rg;
        int m = mt * 128 + wCol + ct * 16 + ln15;
        float v = acc[rt][ct][rg];
        if (v < 0.f) v = 0.f;
        r_bf[((long)ht * 256 + n) * 256 + m] = f2b(v);
      }
}

// ---------------------------------------------------------------------------
__global__ __launch_bounds__(256) void k_qw2(const u16* r_bf, const u16* qW2t, const float* a,
                                             u16* ga) {
  __shared__ u16 shm[16384];
  const int bx = blockIdx.x;
  const int ht = bx >> 2, nt = (bx >> 1) & 1, mt = bx & 1;
  f32x4 acc[4][4];
  zero_acc(acc);
  gemm128(shm, r_bf + ((long)ht * 256 + nt * 128) * 256, qW2t + ((long)ht * 256 + mt * 128) * 256,
          256, 256, 256, acc);
  const int tid = threadIdx.x, lane = tid & 63, wave = tid >> 6;
  const int ln15 = lane & 15, lq = lane >> 4;
  const int wRow = (wave >> 1) * 64, wCol = (wave & 1) * 64;
#pragma unroll
  for (int rt = 0; rt < 4; ++rt)
#pragma unroll
    for (int ct = 0; ct < 4; ++ct)
#pragma unroll
      for (int rg = 0; rg < 4; ++rg) {
        int n = nt * 128 + wRow + rt * 16 + lq * 4 + rg;
        int m = mt * 128 + wCol + ct * 16 + ln15;
        float v = acc[rt][ct][rg];
        float sig = 1.f / (1.f + __expf(-v));
        float gv = sig * a[ht * 256 + m];
        int s = m >> 7, kk = m & 127;
        ga[(((long)ht * 2 + s) * 256 + n) * 128 + kk] = f2b(gv);
      }
}

// ---------------------------------------------------------------------------
__global__ __launch_bounds__(256) void k_w12(const u16* ga, const u16* Wb, u16* w12) {
  __shared__ u16 shm[16384];
  const int bx = blockIdx.x;
  const int c = bx >> 4, r2 = bx & 15;
  const int nt = r2 >> 3, dt = r2 & 7;
  const int ht = c >> 1;
  f32x4 acc[4][4];
  zero_acc(acc);
  gemm128(shm, ga + ((long)c * 256 + nt * 128) * 128, Wb + (long)ht * 131072 + dt * 128 * 128,
          128, 128, 128, acc);
  const int tid = threadIdx.x, lane = tid & 63, wave = tid >> 6;
  const int ln15 = lane & 15, lq = lane >> 4;
  const int wRow = (wave >> 1) * 64, wCol = (wave & 1) * 64;
#pragma unroll
  for (int rt = 0; rt < 4; ++rt)
#pragma unroll
    for (int ct = 0; ct < 4; ++ct)
#pragma unroll
      for (int rg = 0; rg < 4; ++rg) {
        int n = nt * 128 + wRow + rt * 16 + lq * 4 + rg;
        int d = dt * 128 + wCol + ct * 16 + ln15;
        w12[((long)n * 48 + c) * 1024 + d] = f2b(acc[rt][ct][rg]);
      }
}

// ---------------------------------------------------------------------------
__global__ __launch_bounds__(256) void k_f(const u16* x, const u16* w12, float* F) {
  __shared__ u16 shm[16384];
  const int n = blockIdx.x;
  f32x4 acc[4][4];
  zero_acc(acc);
  gemm128(shm, x + (long)n * E_ * D_, w12 + (long)n * 48 * 1024, 1024, 1024, 1024, acc);
  const int tid = threadIdx.x, lane = tid & 63, wave = tid >> 6;
  const int ln15 = lane & 15, lq = lane >> 4;
  const int wRow = (wave >> 1) * 64, wCol = (wave & 1) * 64;
#pragma unroll
  for (int rt = 0; rt < 4; ++rt)
#pragma unroll
    for (int ct = 0; ct < 4; ++ct)
#pragma unroll
      for (int rg = 0; rg < 4; ++rg) {
        int e = wRow + rt * 16 + lq * 4 + rg;
        int c = wCol + ct * 16 + ln15;
        if (e < 105 && c < 48) F[((long)n * 48 + c) * 105 + e] = acc[rt][ct][rg];
      }
}

// ---------------------------------------------------------------------------
// k_h: h_last -> packed transposed bf16 tile inside d_out, CHUNK-MAJOR layout:
//   u16 index t2 = c*1024 + k*8 + e   (c = j>>3 in [0,14), k in [0,128), e = j&7)
//   byte t = 2*t2; placed at out bytes ((n*105 + (t>>9))<<12) + (h<<9) + (t&511)
// (rows 0..55 of the (h,n) column slice — read then overwritten ONLY by k_attn
// block (h,n)). Final store loop iterates DESTINATION order => fully coalesced.
// ---------------------------------------------------------------------------
__global__ __launch_bounds__(256) void k_h(const u16* x, const u16* Wt, const float* nmask,
                                           float* out) {
  __shared__ u16 shm[16384];
  const int bx = blockIdx.x;
  const int h = bx / 210;
  const int ne0 = (bx % 210) * 128;
  f32x4 acc[4][4];
  zero_acc(acc);
  gemm128(shm, x + (long)ne0 * D_, Wt + (long)h * DH_ * D_, 1024, 1024, 1024, acc);
  const int tid = threadIdx.x, lane = tid & 63, wave = tid >> 6;
  const int ln15 = lane & 15, lq = lane >> 4;
  const int wRow = (wave >> 1) * 64, wCol = (wave & 1) * 64;
  // stage transposed bf16 tile: shm[k*128 + (nel ^ ((k&15)<<3))]
#pragma unroll
  for (int rt = 0; rt < 4; ++rt)
#pragma unroll
    for (int ct = 0; ct < 4; ++ct)
#pragma unroll
      for (int rg = 0; rg < 4; ++rg) {
        int nel = wRow + rt * 16 + lq * 4 + rg;
        int k   = wCol + ct * 16 + ln15;
        shm[k * 128 + (nel ^ ((k & 15) << 3))] = f2b(acc[rt][ct][rg]);
      }
  __syncthreads();
  char* ob = (char*)out;
  const int nStart = ne0 / 105;
  const int nEnd   = (ne0 + 127) / 105;
  for (int n = nStart; n <= nEnd; ++n) {
    const long tb = (((long)n * 105) << 12) + ((long)h << 9);
    const int pe = n * 105 + 104;                     // ne holding j=104
    const bool ownPad = (pe >= ne0) && (pe < ne0 + 128);
    for (int t2 = tid; t2 < 14336; t2 += 256) {
      int c = t2 >> 10;
      int r = t2 & 1023;
      int k = r >> 3, e = r & 7;
      int j = c * 8 + e;
      int t = t2 * 2;
      long gb = tb + (long)(t >> 9) * 4096 + (t & 511);
      if (j < 105) {
        int ne = n * 105 + j;
        if (ne >= ne0 && ne < ne0 + 128) {
          int nel = ne - ne0;
          u16 v = shm[k * 128 + (nel ^ ((k & 15) << 3))];
          float mv = nmask[ne];
          *(u16*)(ob + gb) = (mv != 0.f) ? v : (u16)0;
        }
      } else if (ownPad) {
        *(u16*)(ob + gb) = 0;                          // j = 105..111 pad
      }
    }
  }
}

// ---------------------------------------------------------------------------
// k_attn: per (h,n). Phase B: 16-lane-group softmax + depth-1 adj prefetch.
// Phase C: operand-SWAPPED MFMA PV (C^T fragment layout) -> direct float4
// epilogue from acc (+relu +residual). One barrier protects the packed-tile
// read/overwrite ordering. LDS 31744 B, 5 blocks/CU. 2048 blocks.
// ---------------------------------------------------------------------------
__global__ __launch_bounds__(256) void k_attn(const float* F, const int* adj, const u16* x,
                                              float* out) {
  const int h = blockIdx.x >> 8;
  const int n = blockIdx.x & 255;
  __shared__ u16 cb[112 * 128];
  __shared__ float f1s[3][112];
  __shared__ float f2s[3][112];
  const int tid = threadIdx.x;
  const int lane = tid & 63, wave = tid >> 6;

  // ---- phase A: stage F rows; zero ghost slots (chunks 14/15, rows 0..104) ----
  for (int i = tid; i < 630; i += 256) {
    int t = i / 210;
    int rm = i - t * 210;
    int s = rm / 105;
    int e = rm - s * 105;
    float v = F[((long)n * 48 + (h * 3 + t) * 2 + s) * 105 + e];
    if (s == 0) f1s[t][e] = v; else f2s[t][e] = v;
  }
  for (int idx = tid; idx < 1680; idx += 256) {
    int i = idx >> 4, sl = idx & 15;
    int rsw = i & 15;
    int pos = (((14 + (sl >> 3)) ^ rsw) << 3) + (sl & 7);
    cb[i * 128 + pos] = 0;
  }
  __syncthreads();

  // ---- phase B: 16-lane groups; row i = it*16 + wave*4 + g; depth-1 prefetch.
  //      Unguarded 7-col store also writes exact zeros at pad cols j=105..111.
  {
    const int* abase = adj + (long)n * (E_ * E_);
    const int g  = lane >> 4;
    const int lg = lane & 15;
    float f2r[3][7];
#pragma unroll
    for (int m = 0; m < 7; ++m) {
      int j = lg + m * 16;
      bool jv = j < 105;
#pragma unroll
      for (int t = 0; t < 3; ++t) f2r[t][m] = jv ? f2s[t][j] : 0.f;
    }
    int avc[7];
    {
      int i0 = wave * 4 + g;                 // always < 32, valid
#pragma unroll
      for (int m = 0; m < 7; ++m) {
        int j = lg + m * 16;
        avc[m] = (j < 105) ? abase[i0 * E_ + j] : 0;
      }
    }
#pragma unroll
    for (int it = 0; it < 7; ++it) {
      int i = it * 16 + wave * 4 + g;
      bool iv = i < 105;
      int ir = iv ? i : 0;
      int avn[7];
      if (it < 6) {
        int in_ = i + 16;
        bool ivn = in_ < 105;
        int irn = ivn ? in_ : 0;
#pragma unroll
        for (int m = 0; m < 7; ++m) {
          int j = lg + m * 16;
          avn[m] = (ivn && j < 105) ? abase[irn * E_ + j] : 0;
        }
      }
      float f11 = f1s[0][ir], f12 = f1s[1][ir], f13 = f1s[2][ir];
      float s[7];
#pragma unroll
      for (int m = 0; m < 7; ++m) {
        int a_ = avc[m];
        float f1v = (a_ == 1) ? f11 : ((a_ == 2) ? f12 : f13);
        float f2v = (a_ == 1) ? f2r[0][m] : ((a_ == 2) ? f2r[1][m] : f2r[2][m]);
        float sv = f1v + f2v;
        sv = (sv < 0.f) ? 0.2f * sv : sv;
        s[m] = (a_ > 0) ? sv : -1e30f;
      }
      float mm = s[0];
#pragma unroll
      for (int m = 1; m < 7; ++m) mm = fmaxf(mm, s[m]);
#pragma unroll
      for (int d = 1; d < 16; d <<= 1) mm = fmaxf(mm, __shfl_xor(mm, d));
      float e[7];
      float sum = 0.f;
#pragma unroll
      for (int m = 0; m < 7; ++m) {
        int j = lg + m * 16;
        e[m] = (j < 105) ? __expf(s[m] - mm) : 0.f;
        sum += e[m];
      }
#pragma unroll
      for (int d = 1; d < 16; d <<= 1) sum += __shfl_xor(sum, d);
      float inv = 1.f / sum;
      if (iv) {
        const int rsw = i & 15;
#pragma unroll
        for (int m = 0; m < 7; ++m) {
          int j = lg + m * 16;
          cb[i * 128 + ((((j >> 3) ^ rsw) << 3) + (j & 7))] = f2b(e[m] * inv);
        }
      }
      if (it < 6) {
#pragma unroll
        for (int m = 0; m < 7; ++m) avc[m] = avn[m];
      }
    }
  }
  __syncthreads();

  // ---- phase C: PV via operand-swapped MFMA (acc = C^T fragments) ----
  const char* hb = (const char*)out + (((long)n * 105) << 12) + ((long)h << 9);
  const int ln15 = lane & 15, lq = lane >> 4;
  const int nmt = (wave < 3) ? 2 : 1;
  f32x4 acc[2][8];
  {
    f32x4 z = {0.f, 0.f, 0.f, 0.f};
#pragma unroll
    for (int a_ = 0; a_ < 2; ++a_)
#pragma unroll
      for (int b_ = 0; b_ < 8; ++b_) acc[a_][b_] = z;
  }
#pragma unroll
  for (int ks = 0; ks < 4; ++ks) {
    const int cc = ks * 4 + lq;
    const int ccb = (cc < 14) ? cc : 0;  // clamp: matching A(cb) chunks are zero
    bf16x8 bfr[8];
#pragma unroll
    for (int jn = 0; jn < 8; ++jn) {
      int k = jn * 16 + ln15;
      bfr[jn] = *(const bf16x8*)(hb + (long)(ccb * 4 + (k >> 5)) * 4096 + (k & 31) * 16);
    }
    __builtin_amdgcn_s_setprio(1);
#pragma unroll
    for (int im = 0; im < 2; ++im) {
      if (im < nmt) {
        int i = (wave + im * 4) * 16 + ln15;
        bf16x8 af = *(const bf16x8*)&cb[i * 128 + ((cc ^ (i & 15)) << 3)];
#pragma unroll
        for (int jn = 0; jn < 8; ++jn)
          acc[im][jn] = __builtin_amdgcn_mfma_f32_16x16x32_bf16(bfr[jn], af, acc[im][jn], 0, 0, 0);
      }
    }
    __builtin_amdgcn_s_setprio(0);
  }
  // all packed-tile reads must complete before out rows are overwritten
  __syncthreads();

  // ---- epilogue: C^T layout => lane owns row i=ln15(+16*blk), k=jn*16+lq*4+rg.
  //      relu + bf16 residual + direct float4 stores (64B/row/instr, jn pairs
  //      complete each 128B line back-to-back).
  for (int im = 0; im < nmt; ++im) {
    int i = (wave + im * 4) * 16 + ln15;
    if (i < 105) {
      long rb = ((long)(n * E_ + i)) * D_ + h * DH_ + lq * 4;
#pragma unroll
      for (int jn = 0; jn < 8; ++jn) {
        f32x4 v = acc[im][jn];
#pragma unroll
        for (int c = 0; c < 4; ++c) v[c] = v[c] < 0.f ? 0.f : v[c];
        long xb = rb + jn * 16;
        ushort4 xv = *(const ushort4*)&x[xb];
        float4 o;
        o.x = v[0] + b2f(xv.x);
        o.y = v[1] + b2f(xv.y);
        o.z = v[2] + b2f(xv.z);
        o.w = v[3] + b2f(xv.w);
        *(float4*)&out[xb] = o;
      }
    }
  }
}

// ---------------------------------------------------------------------------
extern "C" void kernel_launch(void* const* d_in, const int* in_sizes, int n_in,
                              void* d_out, int out_size, void* d_ws, size_t ws_size,
                              hipStream_t stream) {
  const float* q    = (const float*)d_in[0];
  const float* para = (const float*)d_in[1];
  const float* sent = (const float*)d_in[2];
  const float* ent  = (const float*)d_in[3];
  const float* pm   = (const float*)d_in[4];
  const float* sm   = (const float*)d_in[5];
  const float* em   = (const float*)d_in[6];
  const int*   adj  = (const int*)d_in[7];
  const float* W    = (const float*)d_in[8];
  const float* a    = (const float*)d_in[9];
  const float* qW1  = (const float*)d_in[10];
  const float* qW2  = (const float*)d_in[11];
  float* out = (float*)d_out;
  char* ws = (char*)d_ws;

  u16*   x     = (u16*)(ws);
  float* nmask = (float*)(ws + 55050240);
  u16*   Wb    = (u16*)(ws + 55682048);
  u16*   Wt    = (u16*)(ws + 61973504);
  u16*   qW1t  = (u16*)(ws + 64070656);
  u16*   qW2t  = (u16*)(ws + 76653568);
  u16*   r_bf  = (u16*)(ws + 79799296);
  u16*   ga    = (u16*)(ws + 82945024);
  u16*   w12   = (u16*)(ws + 86090752);
  float* F     = (float*)(ws + 111420416);

  k_build<<<13440, 256, 0, stream>>>(q, para, sent, ent, pm, sm, em, x, nmask);
  k_cast<<<3072, 256, 0, stream>>>(W, Wb, 3145728);
  k_tr<<<dim3(256, 24), 256, 0, stream>>>(qW1, qW1t, 1024, 256, 262144, 262144);
  k_tr<<<dim3(64, 24), 256, 0, stream>>>(qW2, qW2t, 256, 256, 65536, 65536);
  k_tr<<<dim3(128, 8), 256, 0, stream>>>(W + 262144, Wt, 1024, 128, 393216, 131072);
  k_qw1<<<96, 256, 0, stream>>>(x, qW1t, r_bf);
  k_qw2<<<96, 256, 0, stream>>>(r_bf, qW2t, a, ga);
  k_w12<<<768, 256, 0, stream>>>(ga, Wb, w12);
  k_f<<<256, 256, 0, stream>>>(x, w12, F);
  k_h<<<1680, 256, 0, stream>>>(x, Wt, nmask, out);
  k_attn<<<2048, 256, 0, stream>>>(F, adj, x, out);
}